// Round 1
// baseline (2843.371 us; speedup 1.0000x reference)
//
#include <hip/hip_runtime.h>

#define N_NODES 100000
#define IN_F 256
#define OUT_F 128

// ---------------- GEMM: support[N,128] = x[N,256] @ w[256,128] (fp32) -------
// Tile: 64 rows x 128 cols, K-chunks of 64. Block = 256 threads.
// Each thread computes 8 rows x 4 cols. LDS: Xs transposed [k][row] so the
// inner loop is 3 x ds_read_b128 per 32 FMAs.
__global__ __launch_bounds__(256) void gemm_kernel(const float* __restrict__ x,
                                                   const float* __restrict__ w,
                                                   float* __restrict__ support) {
    __shared__ float Xs[64][72];    // [k][row], pad 72 to break conflicts
    __shared__ float Ws[64][128];   // [k][col]

    const int tid = threadIdx.x;
    const int row_base = blockIdx.x * 64;

    // compute assignment: 32 col-groups x 8 row-groups
    const int c0 = (tid & 31) * 4;   // col 0..124
    const int r0 = (tid >> 5) * 8;   // row 0..56

    // load assignment for X: 4 threads per row, 16 contiguous k each
    const int lrow = tid >> 2;       // 0..63
    const int lk   = (tid & 3) * 16; // 0,16,32,48

    float acc[8][4];
#pragma unroll
    for (int r = 0; r < 8; ++r)
#pragma unroll
        for (int c = 0; c < 4; ++c) acc[r][c] = 0.f;

    for (int k0 = 0; k0 < IN_F; k0 += 64) {
        __syncthreads();   // protect previous iteration's reads

        // --- stage X tile (transposed into Xs[k][row]) ---
        int grow = row_base + lrow;
        if (grow >= N_NODES) grow = N_NODES - 1;   // clamp (stores guarded)
        const float4* xp = (const float4*)(x + (size_t)grow * IN_F + k0 + lk);
        float4 xv[4];
#pragma unroll
        for (int j = 0; j < 4; ++j) xv[j] = xp[j];
#pragma unroll
        for (int j = 0; j < 4; ++j) {
            Xs[lk + j * 4 + 0][lrow] = xv[j].x;
            Xs[lk + j * 4 + 1][lrow] = xv[j].y;
            Xs[lk + j * 4 + 2][lrow] = xv[j].z;
            Xs[lk + j * 4 + 3][lrow] = xv[j].w;
        }

        // --- stage W tile: 64x128 floats = 2048 float4, 8 per thread ---
#pragma unroll
        for (int j = 0; j < 8; ++j) {
            int q  = j * 256 + tid;        // coalesced
            int kk = q >> 5;               // 0..63
            int cc = (q & 31) << 2;        // 0..124
            float4 wv = *(const float4*)(w + (size_t)(k0 + kk) * OUT_F + cc);
            *(float4*)&Ws[kk][cc] = wv;
        }

        __syncthreads();

        // --- compute: 64 k-steps, 32 FMAs each ---
#pragma unroll 4
        for (int k = 0; k < 64; ++k) {
            float4 wv = *(const float4*)&Ws[k][c0];
            float4 xa = *(const float4*)&Xs[k][r0];
            float4 xb = *(const float4*)&Xs[k][r0 + 4];
            float xr[8] = {xa.x, xa.y, xa.z, xa.w, xb.x, xb.y, xb.z, xb.w};
            float wr[4] = {wv.x, wv.y, wv.z, wv.w};
#pragma unroll
            for (int r = 0; r < 8; ++r)
#pragma unroll
                for (int c = 0; c < 4; ++c)
                    acc[r][c] += xr[r] * wr[c];
        }
    }

    // --- store ---
#pragma unroll
    for (int r = 0; r < 8; ++r) {
        int grow = row_base + r0 + r;
        if (grow < N_NODES) {
            float4 v = {acc[r][0], acc[r][1], acc[r][2], acc[r][3]};
            *(float4*)(support + (size_t)grow * OUT_F + c0) = v;
        }
    }
}

// ---------------- init: out[n][f] = bias[f] --------------------------------
__global__ __launch_bounds__(256) void init_kernel(float* __restrict__ out,
                                                   const float* __restrict__ bias) {
    int idx = blockIdx.x * 256 + threadIdx.x;          // float4 index
    if (idx >= N_NODES * (OUT_F / 4)) return;
    int f4 = idx & (OUT_F / 4 - 1);                    // 0..31
    ((float4*)out)[idx] = ((const float4*)bias)[f4];
}

// ---------------- SpMM: out[row] += val * support[col] (atomics) ------------
// One wave per edge; each lane handles 2 features (128/64).
__global__ __launch_bounds__(256) void spmm_kernel(const int* __restrict__ adj_row,
                                                   const int* __restrict__ adj_col,
                                                   const float* __restrict__ adj_val,
                                                   const float* __restrict__ support,
                                                   float* __restrict__ out, int E) {
    int e = blockIdx.x * 4 + (threadIdx.x >> 6);
    if (e >= E) return;
    int lane = threadIdx.x & 63;

    int row = adj_row[e];
    int col = adj_col[e];
    float v = adj_val[e];

    float2 s = *((const float2*)(support + (size_t)col * OUT_F) + lane);
    float* op = out + (size_t)row * OUT_F + lane * 2;
    atomicAdd(op + 0, v * s.x);
    atomicAdd(op + 1, v * s.y);
}

// ---------------- relu in-place ---------------------------------------------
__global__ __launch_bounds__(256) void relu_kernel(float* __restrict__ out) {
    int idx = blockIdx.x * 256 + threadIdx.x;          // float4 index
    if (idx >= N_NODES * (OUT_F / 4)) return;
    float4 v = ((float4*)out)[idx];
    v.x = fmaxf(v.x, 0.f); v.y = fmaxf(v.y, 0.f);
    v.z = fmaxf(v.z, 0.f); v.w = fmaxf(v.w, 0.f);
    ((float4*)out)[idx] = v;
}

extern "C" void kernel_launch(void* const* d_in, const int* in_sizes, int n_in,
                              void* d_out, int out_size, void* d_ws, size_t ws_size,
                              hipStream_t stream) {
    const float* x       = (const float*)d_in[0];
    const int*   adj_row = (const int*)d_in[1];
    const int*   adj_col = (const int*)d_in[2];
    const float* adj_val = (const float*)d_in[3];
    const float* weight  = (const float*)d_in[4];
    const float* bias    = (const float*)d_in[5];
    float* out = (float*)d_out;
    float* support = (float*)d_ws;          // N*128 fp32 = 51.2 MB
    const int E = in_sizes[1];

    init_kernel<<<(N_NODES * (OUT_F / 4) + 255) / 256, 256, 0, stream>>>(out, bias);
    gemm_kernel<<<(N_NODES + 63) / 64, 256, 0, stream>>>(x, weight, support);
    spmm_kernel<<<(E + 3) / 4, 256, 0, stream>>>(adj_row, adj_col, adj_val,
                                                 support, out, E);
    relu_kernel<<<(N_NODES * (OUT_F / 4) + 255) / 256, 256, 0, stream>>>(out);
}

// Round 2
// 824.251 us; speedup vs baseline: 3.4496x; 3.4496x over previous
//
#include <hip/hip_runtime.h>

#define N_NODES 100000
#define IN_F 256
#define OUT_F 128

// ---------------- GEMM: support[N,128] = x[N,256] @ w[256,128] (fp32) -------
__global__ __launch_bounds__(256) void gemm_kernel(const float* __restrict__ x,
                                                   const float* __restrict__ w,
                                                   float* __restrict__ support) {
    __shared__ float Xs[64][72];    // [k][row], pad to break conflicts
    __shared__ float Ws[64][128];   // [k][col]

    const int tid = threadIdx.x;
    const int row_base = blockIdx.x * 64;

    const int c0 = (tid & 31) * 4;   // col 0..124
    const int r0 = (tid >> 5) * 8;   // row 0..56

    const int lrow = tid >> 2;       // 0..63
    const int lk   = (tid & 3) * 16; // 0,16,32,48

    float acc[8][4];
#pragma unroll
    for (int r = 0; r < 8; ++r)
#pragma unroll
        for (int c = 0; c < 4; ++c) acc[r][c] = 0.f;

    for (int k0 = 0; k0 < IN_F; k0 += 64) {
        __syncthreads();

        int grow = row_base + lrow;
        if (grow >= N_NODES) grow = N_NODES - 1;
        const float4* xp = (const float4*)(x + (size_t)grow * IN_F + k0 + lk);
        float4 xv[4];
#pragma unroll
        for (int j = 0; j < 4; ++j) xv[j] = xp[j];
#pragma unroll
        for (int j = 0; j < 4; ++j) {
            Xs[lk + j * 4 + 0][lrow] = xv[j].x;
            Xs[lk + j * 4 + 1][lrow] = xv[j].y;
            Xs[lk + j * 4 + 2][lrow] = xv[j].z;
            Xs[lk + j * 4 + 3][lrow] = xv[j].w;
        }

#pragma unroll
        for (int j = 0; j < 8; ++j) {
            int q  = j * 256 + tid;
            int kk = q >> 5;
            int cc = (q & 31) << 2;
            float4 wv = *(const float4*)(w + (size_t)(k0 + kk) * OUT_F + cc);
            *(float4*)&Ws[kk][cc] = wv;
        }

        __syncthreads();

#pragma unroll 4
        for (int k = 0; k < 64; ++k) {
            float4 wv = *(const float4*)&Ws[k][c0];
            float4 xa = *(const float4*)&Xs[k][r0];
            float4 xb = *(const float4*)&Xs[k][r0 + 4];
            float xr[8] = {xa.x, xa.y, xa.z, xa.w, xb.x, xb.y, xb.z, xb.w};
            float wr[4] = {wv.x, wv.y, wv.z, wv.w};
#pragma unroll
            for (int r = 0; r < 8; ++r)
#pragma unroll
                for (int c = 0; c < 4; ++c)
                    acc[r][c] += xr[r] * wr[c];
        }
    }

#pragma unroll
    for (int r = 0; r < 8; ++r) {
        int grow = row_base + r0 + r;
        if (grow < N_NODES) {
            float4 v = {acc[r][0], acc[r][1], acc[r][2], acc[r][3]};
            *(float4*)(support + (size_t)grow * OUT_F + c0) = v;
        }
    }
}

// ---------------- CSR build ---------------------------------------------
__global__ __launch_bounds__(256) void zero_counts_kernel(int* __restrict__ counts) {
    int i = blockIdx.x * 256 + threadIdx.x;
    if (i < N_NODES) counts[i] = 0;
}

__global__ __launch_bounds__(256) void hist_kernel(const int* __restrict__ adj_row,
                                                   int* __restrict__ counts, int E) {
    int e = blockIdx.x * 256 + threadIdx.x;
    if (e < E) atomicAdd(&counts[adj_row[e]], 1);
}

// block-level sums: each block of 256 reduces 256 counts -> blockSums[b]
__global__ __launch_bounds__(256) void scan1_kernel(const int* __restrict__ counts,
                                                    int* __restrict__ blockSums) {
    __shared__ int tmp[256];
    int i = blockIdx.x * 256 + threadIdx.x;
    int v = (i < N_NODES) ? counts[i] : 0;
    tmp[threadIdx.x] = v;
    __syncthreads();
    for (int off = 128; off > 0; off >>= 1) {
        if (threadIdx.x < off) tmp[threadIdx.x] += tmp[threadIdx.x + off];
        __syncthreads();
    }
    if (threadIdx.x == 0) blockSums[blockIdx.x] = tmp[0];
}

// exclusive scan of blockSums (nb <= 512), one block of 512 threads
__global__ __launch_bounds__(512) void scan2_kernel(int* __restrict__ blockSums, int nb) {
    __shared__ int tmp[512];
    int tid = threadIdx.x;
    int v = (tid < nb) ? blockSums[tid] : 0;
    tmp[tid] = v;
    __syncthreads();
    for (int off = 1; off < 512; off <<= 1) {
        int t = (tid >= off) ? tmp[tid - off] : 0;
        __syncthreads();
        if (tid >= off) tmp[tid] += t;
        __syncthreads();
    }
    if (tid < nb) blockSums[tid] = tmp[tid] - v;   // exclusive
}

// per-block exclusive scan + base -> starts & cursor
__global__ __launch_bounds__(256) void scan3_kernel(const int* __restrict__ counts,
                                                    const int* __restrict__ blockSums,
                                                    int* __restrict__ starts,
                                                    int* __restrict__ cursor) {
    __shared__ int tmp[256];
    int tid = threadIdx.x;
    int i = blockIdx.x * 256 + tid;
    int v = (i < N_NODES) ? counts[i] : 0;
    tmp[tid] = v;
    __syncthreads();
    for (int off = 1; off < 256; off <<= 1) {
        int t = (tid >= off) ? tmp[tid - off] : 0;
        __syncthreads();
        if (tid >= off) tmp[tid] += t;
        __syncthreads();
    }
    if (i < N_NODES) {
        int excl = tmp[tid] - v + blockSums[blockIdx.x];
        starts[i] = excl;
        cursor[i] = excl;
    }
}

__global__ __launch_bounds__(256) void scatter_kernel(const int* __restrict__ adj_row,
                                                      const int* __restrict__ adj_col,
                                                      const float* __restrict__ adj_val,
                                                      int* __restrict__ cursor,
                                                      int2* __restrict__ edges, int E) {
    int e = blockIdx.x * 256 + threadIdx.x;
    if (e >= E) return;
    int row = adj_row[e];
    int pos = atomicAdd(&cursor[row], 1);
    int2 packed;
    packed.x = adj_col[e];
    packed.y = __float_as_int(adj_val[e]);
    edges[pos] = packed;
}

// ---------------- gather SpMM + bias + relu ---------------------------------
// One wave per node; lane handles 2 features. Unroll 4 edges for ILP.
__global__ __launch_bounds__(256) void gather_kernel(const int* __restrict__ starts,
                                                     const int* __restrict__ counts,
                                                     const int2* __restrict__ edges,
                                                     const float* __restrict__ support,
                                                     const float* __restrict__ bias,
                                                     float* __restrict__ out) {
    int node = blockIdx.x * 4 + (threadIdx.x >> 6);
    if (node >= N_NODES) return;
    int lane = threadIdx.x & 63;

    int deg   = counts[node];
    int start = starts[node];

    float2 acc = {0.f, 0.f};
    int i = 0;
    for (; i + 4 <= deg; i += 4) {
        int2 e0 = edges[start + i + 0];
        int2 e1 = edges[start + i + 1];
        int2 e2 = edges[start + i + 2];
        int2 e3 = edges[start + i + 3];
        float2 s0 = *((const float2*)(support + (size_t)e0.x * OUT_F) + lane);
        float2 s1 = *((const float2*)(support + (size_t)e1.x * OUT_F) + lane);
        float2 s2 = *((const float2*)(support + (size_t)e2.x * OUT_F) + lane);
        float2 s3 = *((const float2*)(support + (size_t)e3.x * OUT_F) + lane);
        float v0 = __int_as_float(e0.y), v1 = __int_as_float(e1.y);
        float v2 = __int_as_float(e2.y), v3 = __int_as_float(e3.y);
        acc.x += v0 * s0.x; acc.y += v0 * s0.y;
        acc.x += v1 * s1.x; acc.y += v1 * s1.y;
        acc.x += v2 * s2.x; acc.y += v2 * s2.y;
        acc.x += v3 * s3.x; acc.y += v3 * s3.y;
    }
    for (; i < deg; ++i) {
        int2 e = edges[start + i];
        float2 s = *((const float2*)(support + (size_t)e.x * OUT_F) + lane);
        float v = __int_as_float(e.y);
        acc.x += v * s.x; acc.y += v * s.y;
    }

    float2 b = *((const float2*)bias + lane);
    float2 r;
    r.x = fmaxf(acc.x + b.x, 0.f);
    r.y = fmaxf(acc.y + b.y, 0.f);
    *((float2*)(out + (size_t)node * OUT_F) + lane) = r;
}

extern "C" void kernel_launch(void* const* d_in, const int* in_sizes, int n_in,
                              void* d_out, int out_size, void* d_ws, size_t ws_size,
                              hipStream_t stream) {
    const float* x       = (const float*)d_in[0];
    const int*   adj_row = (const int*)d_in[1];
    const int*   adj_col = (const int*)d_in[2];
    const float* adj_val = (const float*)d_in[3];
    const float* weight  = (const float*)d_in[4];
    const float* bias    = (const float*)d_in[5];
    float* out = (float*)d_out;
    const int E = in_sizes[1];

    // workspace layout (16B-aligned chunks)
    char* ws = (char*)d_ws;
    float* support   = (float*)ws;                        ws += (size_t)N_NODES * OUT_F * 4;  // 51.2 MB
    int2*  edges     = (int2*)ws;                         ws += (size_t)E * 8;                // 25.6 MB
    int*   counts    = (int*)ws;                          ws += (size_t)N_NODES * 4;
    int*   starts    = (int*)ws;                          ws += (size_t)N_NODES * 4;
    int*   cursor    = (int*)ws;                          ws += (size_t)N_NODES * 4;
    int*   blockSums = (int*)ws;                          ws += 512 * 4;

    const int nbN = (N_NODES + 255) / 256;   // 391 blocks over nodes
    const int nbE = (E + 255) / 256;

    gemm_kernel<<<(N_NODES + 63) / 64, 256, 0, stream>>>(x, weight, support);

    zero_counts_kernel<<<nbN, 256, 0, stream>>>(counts);
    hist_kernel<<<nbE, 256, 0, stream>>>(adj_row, counts, E);
    scan1_kernel<<<nbN, 256, 0, stream>>>(counts, blockSums);
    scan2_kernel<<<1, 512, 0, stream>>>(blockSums, nbN);
    scan3_kernel<<<nbN, 256, 0, stream>>>(counts, blockSums, starts, cursor);
    scatter_kernel<<<nbE, 256, 0, stream>>>(adj_row, adj_col, adj_val, cursor, edges, E);

    gather_kernel<<<(N_NODES + 3) / 4, 256, 0, stream>>>(starts, counts, edges,
                                                         support, bias, out);
}